// Round 6
// baseline (1624.162 us; speedup 1.0000x reference)
//
#include <hip/hip_runtime.h>
#include <cstdint>
#include <cstddef>

#define H 450
#define H2 900
#define KP 480
#define KP2 960
#define NMESS 10241
#define NNODE 5120
#define MPAD 10368                 // 81 * 128
#define PSZ ((size_t)MPAD * KP)    // plane size in shorts = 4,976,640
#define KM 5
#define KN 6
#define LDI 1350                   // CH row stride (c_z | c_h | r1b)

typedef __attribute__((ext_vector_type(8))) short short8;   // 8 bf16
typedef __attribute__((ext_vector_type(4))) float f32x4;

__device__ __forceinline__ short bf16rne(float f) {
  union { float f; unsigned u; } x; x.f = f;
  unsigned u = x.u;
  u += 0x7FFF + ((u >> 16) & 1);
  return (short)(u >> 16);
}
__device__ __forceinline__ float bf16tof(short s) {
  union { float f; unsigned u; } x;
  x.u = ((unsigned)(unsigned short)s) << 16;
  return x.f;
}
__device__ __forceinline__ void bf16split(float v, short& hi, short& lo) {
  hi = bf16rne(v);
  lo = bf16rne(v - bf16tof(hi));
}
__device__ __forceinline__ float sigmoidf_(float x) {
  return 1.f / (1.f + __expf(-x));
}

// ---------------- split-bf16 MFMA GEMM v4 ----------------
// 256 threads (4 waves, 64x64 wave tiles), BM=BN=128, BK=32.
// hi|lo planes packed into one 128B LDS row, XOR bank-swizzle (row&7)<<3,
// double-buffered, XCD-chunked block swizzle, optional fused GRU epilogue.
#define BM 128
#define BN 128
#define BK 32

// OUT: 0 = f32 C (+bias, opt relu)   2 = fused tz->combine, writes h planes
template<int ACT, int OUT>
__global__ __launch_bounds__(256, 2)
void gemm3(const short* __restrict__ Ah, const short* __restrict__ Al, int Kpad,
           const short* __restrict__ Bth, const short* __restrict__ Btl,
           const float* __restrict__ bias,
           float* C, int ldc, int M, int N,
           const float* __restrict__ CHp,   // [M][1350]: c_z | c_h | r1b
           const float* __restrict__ thp,   // [M][450] t_h
           const short* __restrict__ smh, const short* __restrict__ sml,
           short* oh, short* ol)            // h planes out
{
  __shared__ short As[2][BM][64];   // hi halves [0,32), lo [32,64); swizzled
  __shared__ short Bs[2][BN][64];

  // ---- XCD-chunked bijective swizzle (m204) ----
  const int gx = gridDim.x;
  const int nwg = gx * gridDim.y;
  int lid = blockIdx.y * gx + blockIdx.x;
  const int q = nwg >> 3, r = nwg & 7;
  const int xcd = lid & 7, seq = lid >> 3;
  int sid = (xcd < r) ? (xcd * (q + 1) + seq)
                      : (r * (q + 1) + (xcd - r) * q + seq);
  const int bm = (sid / gx) * BM;
  const int bn = (sid % gx) * BN;

  const int tid  = threadIdx.x;
  const int lane = tid & 63;
  const int wid  = tid >> 6;          // 0..3
  const int wm   = (wid >> 1) * 64;
  const int wn   = (wid & 1) * 64;
  const int l15  = lane & 15;
  const int s8   = (lane >> 4) * 8;   // k sub-offset in halves
  const int rr0  = (lane >> 4) * 4;

  // staging: thread -> row ar (0..127), half-offset ak (0 or 16)
  const int ar = tid >> 1;
  const int ak = (tid & 1) * 16;
  const int xw = (ar & 7) << 3;       // write-side XOR (halves)

  const short* Aph = Ah  + (size_t)(bm + ar) * Kpad + ak;
  const short* Apl = Al  + (size_t)(bm + ar) * Kpad + ak;
  const short* Bph = Bth + (size_t)(bn + ar) * Kpad + ak;
  const short* Bpl = Btl + (size_t)(bn + ar) * Kpad + ak;
  const int nk = Kpad / BK;

  f32x4 acc[4][4];
#pragma unroll
  for (int i = 0; i < 4; ++i)
#pragma unroll
    for (int j = 0; j < 4; ++j)
#pragma unroll
      for (int t = 0; t < 4; ++t) acc[i][j][t] = 0.f;

  short8 rah0, rah1, ral0, ral1, rbh0, rbh1, rbl0, rbl1;
  auto LOAD = [&](int t) {
    const int k = t * BK;
    rah0 = *(const short8*)&Aph[k];   rah1 = *(const short8*)&Aph[k + 8];
    ral0 = *(const short8*)&Apl[k];   ral1 = *(const short8*)&Apl[k + 8];
    rbh0 = *(const short8*)&Bph[k];   rbh1 = *(const short8*)&Bph[k + 8];
    rbl0 = *(const short8*)&Bpl[k];   rbl1 = *(const short8*)&Bpl[k + 8];
  };
  auto STORE = [&](int b) {
    *(short8*)&As[b][ar][(ak)      ^ xw] = rah0;
    *(short8*)&As[b][ar][(ak + 8)  ^ xw] = rah1;
    *(short8*)&As[b][ar][(ak + 32) ^ xw] = ral0;
    *(short8*)&As[b][ar][(ak + 40) ^ xw] = ral1;
    *(short8*)&Bs[b][ar][(ak)      ^ xw] = rbh0;
    *(short8*)&Bs[b][ar][(ak + 8)  ^ xw] = rbh1;
    *(short8*)&Bs[b][ar][(ak + 32) ^ xw] = rbl0;
    *(short8*)&Bs[b][ar][(ak + 40) ^ xw] = rbl1;
  };

  LOAD(0); STORE(0);
  __syncthreads();
  int cur = 0;
  for (int t = 0; t < nk; ++t) {
    if (t + 1 < nk) LOAD(t + 1);
    short8 ah[4], al[4], bh[4], bl[4];
#pragma unroll
    for (int i = 0; i < 4; ++i) {
      const int rA = wm + i*16 + l15;
      const int xr = (rA & 7) << 3;
      ah[i] = *(const short8*)&As[cur][rA][(s8)      ^ xr];
      al[i] = *(const short8*)&As[cur][rA][(s8 + 32) ^ xr];
    }
#pragma unroll
    for (int j = 0; j < 4; ++j) {
      const int rB = wn + j*16 + l15;
      const int xr = (rB & 7) << 3;
      bh[j] = *(const short8*)&Bs[cur][rB][(s8)      ^ xr];
      bl[j] = *(const short8*)&Bs[cur][rB][(s8 + 32) ^ xr];
    }
#pragma unroll
    for (int j = 0; j < 4; ++j)
#pragma unroll
      for (int i = 0; i < 4; ++i) {
        acc[i][j] = __builtin_amdgcn_mfma_f32_16x16x32_bf16(ah[i], bh[j], acc[i][j], 0, 0, 0);
        acc[i][j] = __builtin_amdgcn_mfma_f32_16x16x32_bf16(al[i], bh[j], acc[i][j], 0, 0, 0);
        acc[i][j] = __builtin_amdgcn_mfma_f32_16x16x32_bf16(ah[i], bl[j], acc[i][j], 0, 0, 0);
      }
    if (t + 1 < nk) STORE(cur ^ 1);
    __syncthreads();
    cur ^= 1;
  }

#pragma unroll
  for (int j = 0; j < 4; ++j) {
    int col = bn + wn + j*16 + l15;
    if (col >= N) continue;
    float bv = (OUT == 0 && bias) ? bias[col] : 0.f;
#pragma unroll
    for (int i = 0; i < 4; ++i) {
      int row0 = bm + wm + i*16 + rr0;
#pragma unroll
      for (int rr = 0; rr < 4; ++rr) {
        int row = row0 + rr;
        if (row >= M) continue;
        float v = acc[i][j][rr] + bv;
        if (OUT == 0) {
          if (ACT == 1) v = fmaxf(v, 0.f);
          C[(size_t)row * ldc + col] = v;
        } else {
          // fused: v = t_z ; h = mask*((1-z)*sum_h + z*tanh(c_h + t_h))
          size_t oc = (size_t)row * LDI + col;
          size_t op = (size_t)row * KP + col;
          float z     = sigmoidf_(CHp[oc] + v);
          float sum_h = bf16tof(smh[op]) + bf16tof(sml[op]);
          float pre   = tanhf(CHp[oc + 450] + thp[(size_t)row * H + col]);
          float hv    = (1.f - z) * sum_h + z * pre;
          if (row == 0) hv = 0.f;
          short hi, lo; bf16split(hv, hi, lo);
          oh[op] = hi; ol[op] = lo;
        }
      }
    }
  }
}

// ---------------- weight transpose + bf16 hi/lo split ----------------
// Bt[c][k] = W[k][c] for c < rmax (rows >= Kreal / cols >= H zero-filled)
__global__ __launch_bounds__(256)
void k_wT(const float* __restrict__ W, int Kreal,
          short* __restrict__ Bth, short* __restrict__ Btl, int Kpad, int rmax) {
  __shared__ float T[32][33];
  const int tx = threadIdx.x & 31;
  const int ty = threadIdx.x >> 5;
  const int k0 = blockIdx.x * 32;
  const int c0 = blockIdx.y * 32;
#pragma unroll
  for (int i = 0; i < 4; ++i) {
    int k = k0 + ty + i*8, c = c0 + tx;
    T[ty + i*8][tx] = (k < Kreal && c < H) ? W[(size_t)k * H + c] : 0.f;
  }
  __syncthreads();
#pragma unroll
  for (int i = 0; i < 4; ++i) {
    int c = c0 + ty + i*8, k = k0 + tx;
    if (k < Kpad && c < rmax) {
      short hi, lo;
      bf16split(T[tx][ty + i*8], hi, lo);
      Bth[(size_t)c * Kpad + k] = hi;
      Btl[(size_t)c * Kpad + k] = lo;
    }
  }
}

__global__ void k_biascat(const float* __restrict__ bz, const float* __restrict__ bh,
                          const float* __restrict__ bu, float* __restrict__ biasI) {
  int c = blockIdx.x * blockDim.x + threadIdx.x;
  if (c >= 1408) return;
  float v = 0.f;
  if (c < 450) v = bz[c];
  else if (c < 900) v = bh[c - 450];
  else if (c < 1350) v = bu[c - 900];
  biasI[c] = v;
}

// ---------------- elementwise / gather kernels ----------------

__global__ void k_build_idx(const int* __restrict__ fnode,
                            const int* __restrict__ fmess,
                            int* __restrict__ idxM) {
  int m = blockIdx.x * blockDim.x + threadIdx.x;
  if (m < NMESS) idxM[m] = fnode[fmess[m]];
}

__global__ void k_embsplit(const float* __restrict__ emb,
                           const int* __restrict__ idxM,
                           short* __restrict__ eh, short* __restrict__ el) {
  int m = blockIdx.x, j = threadIdx.x * 2;
  if (j >= H) return;
  float2 v = *(const float2*)&emb[(size_t)idxM[m] * H + j];
  short2 h2, l2;
  bf16split(v.x, h2.x, l2.x); bf16split(v.y, h2.y, l2.y);
  size_t o = (size_t)m * KP + j;
  *(short2*)&eh[o] = h2; *(short2*)&el[o] = l2;
}

// one pass over neighbors: sum_h planes + sum_gh planes
__global__ void k_gather2(const short* __restrict__ hh, const short* __restrict__ hl,
                          const float* __restrict__ g,
                          const float* __restrict__ CHp,   // r1b at +900, stride LDI
                          const int* __restrict__ mg,
                          short* __restrict__ shh, short* __restrict__ shl,
                          short* __restrict__ ghh, short* __restrict__ ghl) {
  int m = blockIdx.x, j = threadIdx.x * 2;
  if (j >= H) return;
  const int* e = mg + (size_t)m * KM;
  float2 rb = *(const float2*)&CHp[(size_t)m * LDI + 900 + j];
  float s0 = 0.f, s1 = 0.f, t0 = 0.f, t1 = 0.f;
#pragma unroll
  for (int k = 0; k < KM; ++k) {
    int ek = e[k];
    size_t oP = (size_t)ek * KP + j;
    float2 gv = *(const float2*)&g[(size_t)ek * H + j];
    short2 ph = *(const short2*)&hh[oP];
    short2 pl = *(const short2*)&hl[oP];
    float h0 = bf16tof(ph.x) + bf16tof(pl.x);
    float h1 = bf16tof(ph.y) + bf16tof(pl.y);
    s0 += h0;                          s1 += h1;
    t0 += sigmoidf_(rb.x + gv.x) * h0; t1 += sigmoidf_(rb.y + gv.y) * h1;
  }
  size_t o = (size_t)m * KP + j;
  short2 h2, l2;
  bf16split(s0, h2.x, l2.x); bf16split(s1, h2.y, l2.y);
  *(short2*)&shh[o] = h2; *(short2*)&shl[o] = l2;
  bf16split(t0, h2.x, l2.x); bf16split(t1, h2.y, l2.y);
  *(short2*)&ghh[o] = h2; *(short2*)&ghl[o] = l2;
}

// Acat planes [n][960] = [split(emb[fnode[n]]), split(sum_k h[ng[n,k]]), 0-pad]
__global__ void k_nodecat(const float* __restrict__ emb,
                          const int* __restrict__ fnode,
                          const short* __restrict__ hh, const short* __restrict__ hl,
                          const int* __restrict__ ng,
                          short* __restrict__ Ah, short* __restrict__ Al) {
  int n = blockIdx.x, t = threadIdx.x, j = t * 2;
  if (j < H) {
    float2 v = *(const float2*)&emb[(size_t)fnode[n] * H + j];
    short2 h2, l2;
    bf16split(v.x, h2.x, l2.x); bf16split(v.y, h2.y, l2.y);
    size_t o = (size_t)n * KP2 + j;
    *(short2*)&Ah[o] = h2; *(short2*)&Al[o] = l2;

    const int* e = ng + (size_t)n * KN;
    float s0 = 0.f, s1 = 0.f;
#pragma unroll
    for (int k = 0; k < KN; ++k) {
      size_t oP = (size_t)e[k] * KP + j;
      short2 ph = *(const short2*)&hh[oP];
      short2 pl = *(const short2*)&hl[oP];
      s0 += bf16tof(ph.x) + bf16tof(pl.x);
      s1 += bf16tof(ph.y) + bf16tof(pl.y);
    }
    bf16split(s0, h2.x, l2.x); bf16split(s1, h2.y, l2.y);
    o = (size_t)n * KP2 + H + j;
    *(short2*)&Ah[o] = h2; *(short2*)&Al[o] = l2;
  }
  if (t < 30) {   // zero cols [900,960)
    short2 z2; z2.x = 0; z2.y = 0;
    size_t o = (size_t)n * KP2 + H2 + t * 2;
    *(short2*)&Ah[o] = z2; *(short2*)&Al[o] = z2;
  }
}

// ---------------- launch ----------------

extern "C" void kernel_launch(void* const* d_in, const int* in_sizes, int n_in,
                              void* d_out, int out_size, void* d_ws, size_t ws_size,
                              hipStream_t stream) {
  (void)in_sizes; (void)n_in; (void)out_size; (void)ws_size;

  const int*   fnode      = (const int*)d_in[0];
  const int*   fmess      = (const int*)d_in[1];
  const int*   node_graph = (const int*)d_in[2];
  const int*   mess_graph = (const int*)d_in[3];
  const float* emb        = (const float*)d_in[4];
  const float* Wz         = (const float*)d_in[5];
  const float* bz         = (const float*)d_in[6];
  const float* Wr         = (const float*)d_in[7];
  const float* Ur         = (const float*)d_in[8];
  const float* bu         = (const float*)d_in[9];
  const float* Wh         = (const float*)d_in[10];
  const float* bh         = (const float*)d_in[11];
  const float* Wo         = (const float*)d_in[12];
  const float* bo         = (const float*)d_in[13];

  // ---- workspace (123.5 MB, proven budget) ----
  float* CH  = (float*)d_ws;                       // [M][1350]: c_z|c_h|r1b
  float* g   = CH + (size_t)NMESS * LDI;           // [M][450]: Ur out, then t_h
  short* P   = (short*)(g + (size_t)NMESS * H);
  short* hSh  = P;
  short* hSl  = P + 1 * PSZ;
  short* shSh = P + 2 * PSZ;     // sum_h hi (later Acat hi, stride 960)
  short* shSl = P + 3 * PSZ;
  short* ghSh = P + 4 * PSZ;     // sum_gh hi (also fmess_e hi)

  // ---- d_out messages region (17.6 of 18.4 MB) ----
  char*  scr   = (char*)d_out + (size_t)NNODE * H * 4;
  int*   idxM  = (int*)scr;                          // 40,964 B
  float* biasI = (float*)(scr + 40976);              // 1408 f32
  short* BtIh  = (short*)(scr + 46608);              // [1408][480]
  short* BtIl  = BtIh  + (size_t)1408 * KP;
  short* BtUrh = BtIl  + (size_t)1408 * KP;          // [512][480] each below
  short* BtUrl = BtUrh + (size_t)512 * KP;
  short* BtZh  = BtUrl + (size_t)512 * KP;           // Wz bottom
  short* BtZl  = BtZh  + (size_t)512 * KP;
  short* BtHh  = BtZl  + (size_t)512 * KP;           // Wh bottom
  short* BtHl  = BtHh  + (size_t)512 * KP;
  short* BtOh  = BtHl  + (size_t)512 * KP;           // Wo [512][960]
  short* BtOl  = BtOh  + (size_t)512 * KP2;
  short* ghSl  = BtOl  + (size_t)512 * KP2;          // sum_gh lo plane

  // zero planes (pads must be 0 / h0 = 0) + scratch region
  hipMemsetAsync(P, 0, 5 * PSZ * sizeof(short), stream);
  hipMemsetAsync(scr, 0, (size_t)NMESS * H * sizeof(float), stream);

  k_build_idx<<<(NMESS + 255) / 256, 256, 0, stream>>>(fnode, fmess, idxM);

  // weight prep: merged invariant [Wz_t | Wh_t | Wr] rows 0/450/900, then GRU/out mats
  dim3 gT(KP / 32, 16), gT2(KP2 / 32, 16);
  k_wT<<<gT,  256, 0, stream>>>(Wz,                  H, BtIh,            BtIl,            KP, 512);
  k_wT<<<gT,  256, 0, stream>>>(Wh,                  H, BtIh + 450 * KP, BtIl + 450 * KP, KP, 512);
  k_wT<<<gT,  256, 0, stream>>>(Wr,                  H, BtIh + 900 * KP, BtIl + 900 * KP, KP, 508);
  k_wT<<<gT,  256, 0, stream>>>(Ur,                  H, BtUrh, BtUrl, KP, 512);
  k_wT<<<gT,  256, 0, stream>>>(Wz + (size_t)H * H,  H, BtZh,  BtZl,  KP, 512);
  k_wT<<<gT,  256, 0, stream>>>(Wh + (size_t)H * H,  H, BtHh,  BtHl,  KP, 512);
  k_wT<<<gT2, 256, 0, stream>>>(Wo,                 H2, BtOh,  BtOl,  KP2, 512);
  k_biascat<<<6, 256, 0, stream>>>(bz, bh, bu, biasI);

  // fmess_e split into ghS pair
  k_embsplit<<<NMESS, 256, 0, stream>>>(emb, idxM, ghSh, ghSl);

  // merged invariant GEMM: CH = fmess_e @ [WzT|WhT|Wr] + [bz|bh|bu]
  dim3 gI(11, MPAD / BM);
  gemm3<0,0><<<gI, 256, 0, stream>>>(ghSh, ghSl, KP, BtIh, BtIl, biasI,
                                     CH, LDI, NMESS, LDI,
                                     nullptr, nullptr, nullptr, nullptr, nullptr, nullptr);

  dim3 gB(4, MPAD / BM);
  for (int d = 0; d < 8; ++d) {
    // g = h @ Ur
    gemm3<0,0><<<gB, 256, 0, stream>>>(hSh, hSl, KP, BtUrh, BtUrl, nullptr,
                                       g, H, NMESS, H,
                                       nullptr, nullptr, nullptr, nullptr, nullptr, nullptr);
    // sum_h & sum_gh planes in one pass
    k_gather2<<<NMESS, 256, 0, stream>>>(hSh, hSl, g, CH, mess_graph, shSh, shSl, ghSh, ghSl);
    // t_h = sum_gh @ WhB -> g (dead)
    gemm3<0,0><<<gB, 256, 0, stream>>>(ghSh, ghSl, KP, BtHh, BtHl, nullptr,
                                       g, H, NMESS, H,
                                       nullptr, nullptr, nullptr, nullptr, nullptr, nullptr);
    // t_z = sum_h @ WzB, fused combine -> h planes
    gemm3<0,2><<<gB, 256, 0, stream>>>(shSh, shSl, KP, BtZh, BtZl, nullptr,
                                       nullptr, 0, NMESS, H,
                                       CH, g, shSh, shSl, hSh, hSl);
  }

  // Acat planes (stride 960) then output GEMM with relu
  k_nodecat<<<NNODE, 256, 0, stream>>>(emb, fnode, hSh, hSl, node_graph, shSh, shSl);
  dim3 gF(4, NNODE / BM);
  gemm3<1,0><<<gF, 256, 0, stream>>>(shSh, shSl, KP2, BtOh, BtOl, bo,
                                     (float*)d_out, H, NNODE, H,
                                     nullptr, nullptr, nullptr, nullptr, nullptr, nullptr);

  // messages output = zeros (wipes idx + weights + ghSl) — AFTER final GEMM
  hipMemsetAsync((float*)d_out + (size_t)NNODE * H, 0, (size_t)NMESS * H * sizeof(float), stream);
}

// Round 7
// 1581.269 us; speedup vs baseline: 1.0271x; 1.0271x over previous
//
#include <hip/hip_runtime.h>
#include <cstdint>
#include <cstddef>

#define H 450
#define H2 900
#define KP 480
#define KP2 960
#define NMESS 10241
#define NNODE 5120
#define MPAD 10368                 // 81 * 128
#define PSZ ((size_t)MPAD * KP)    // plane size in shorts = 4,976,640
#define KM 5
#define KN 6
#define LDI 1350                   // CH row stride (c_z | c_h | r1b)

typedef __attribute__((ext_vector_type(8))) short short8;   // 8 bf16
typedef __attribute__((ext_vector_type(4))) float f32x4;

__device__ __forceinline__ short bf16rne(float f) {
  union { float f; unsigned u; } x; x.f = f;
  unsigned u = x.u;
  u += 0x7FFF + ((u >> 16) & 1);
  return (short)(u >> 16);
}
__device__ __forceinline__ float bf16tof(short s) {
  union { float f; unsigned u; } x;
  x.u = ((unsigned)(unsigned short)s) << 16;
  return x.f;
}
__device__ __forceinline__ void bf16split(float v, short& hi, short& lo) {
  hi = bf16rne(v);
  lo = bf16rne(v - bf16tof(hi));
}
__device__ __forceinline__ float sigmoidf_(float x) {
  return 1.f / (1.f + __expf(-x));
}

// direct global->LDS 16B DMA (LDS dest: wave-uniform base + lane*16)
__device__ __forceinline__ void gll16(const short* g, short* l) {
  __builtin_amdgcn_global_load_lds(
      (const __attribute__((address_space(1))) void*)g,
      (__attribute__((address_space(3))) void*)l, 16, 0, 0);
}

// ---------------- split-bf16 MFMA GEMM v5 ----------------
// 256 threads (4 waves, 64x64 wave tiles), BM=BN=128, BK=32.
// global_load_lds staging with pre-swizzled per-lane SOURCE (m201 pattern):
// LDS linear fill, data slot = (lane&7) ^ (row&7); read-side XOR unchanged.
// Double-buffered, XCD-chunked block swizzle, optional fused GRU epilogue.
#define BM 128
#define BN 128
#define BK 32

// OUT: 0 = f32 C (+bias, opt relu)   2 = fused tz->combine, writes h planes
template<int ACT, int OUT>
__global__ __launch_bounds__(256, 2)
void gemm3(const short* __restrict__ Ah, const short* __restrict__ Al, int Kpad,
           const short* __restrict__ Bth, const short* __restrict__ Btl,
           const float* __restrict__ bias,
           float* C, int ldc, int M, int N,
           const float* __restrict__ CHp,   // [M][1350]: c_z | c_h | r1b
           const float* __restrict__ thp,   // [M][450] t_h
           const short* __restrict__ smh, const short* __restrict__ sml,
           short* oh, short* ol)            // h planes out
{
  __shared__ short As[2][BM][64];   // slot s holds data slot s^(row&7); hi slots 0-3, lo 4-7
  __shared__ short Bs[2][BN][64];

  // ---- XCD-chunked bijective swizzle (m204) ----
  const int gx = gridDim.x;
  const int nwg = gx * gridDim.y;
  int lid = blockIdx.y * gx + blockIdx.x;
  const int q = nwg >> 3, r = nwg & 7;
  const int xcd = lid & 7, seq = lid >> 3;
  int sid = (xcd < r) ? (xcd * (q + 1) + seq)
                      : (r * (q + 1) + (xcd - r) * q + seq);
  const int bm = (sid / gx) * BM;
  const int bn = (sid % gx) * BN;

  const int tid  = threadIdx.x;
  const int lane = tid & 63;
  const int wid  = tid >> 6;          // 0..3
  const int wm   = (wid >> 1) * 64;
  const int wn   = (wid & 1) * 64;
  const int l15  = lane & 15;
  const int s8   = (lane >> 4) * 8;   // k sub-offset in halves
  const int rr0  = (lane >> 4) * 4;

  // ---- gload_lds staging assignment ----
  // per wave: 4 sub-tiles of 8 rows x 8 slots for A and B each.
  // lane -> row offset lr = lane>>3, linear LDS slot sl = lane&7.
  // data slot t = sl ^ lr  (rows within sub-tile have row&7 == lr).
  const int lr = lane >> 3;
  const int sl = lane & 7;
  const int t0 = sl ^ lr;
  const int awb = wid * 32;           // wave's row base in the 128-row tile
  const short* srcA[4];
  const short* srcB[4];
#pragma unroll
  for (int qq = 0; qq < 4; ++qq) {
    const int rowA = bm + awb + qq * 8 + lr;
    const int rowB = bn + awb + qq * 8 + lr;
    srcA[qq] = (t0 < 4) ? (Ah + (size_t)rowA * Kpad + t0 * 8)
                        : (Al + (size_t)rowA * Kpad + (t0 - 4) * 8);
    srcB[qq] = (t0 < 4) ? (Bth + (size_t)rowB * Kpad + t0 * 8)
                        : (Btl + (size_t)rowB * Kpad + (t0 - 4) * 8);
  }
  const int nk = Kpad / BK;

  f32x4 acc[4][4];
#pragma unroll
  for (int i = 0; i < 4; ++i)
#pragma unroll
    for (int j = 0; j < 4; ++j)
#pragma unroll
      for (int t = 0; t < 4; ++t) acc[i][j][t] = 0.f;

  // prologue: fill buf 0
#pragma unroll
  for (int qq = 0; qq < 4; ++qq) {
    gll16(srcA[qq], &As[0][awb + qq * 8][0]);
    gll16(srcB[qq], &Bs[0][awb + qq * 8][0]);
  }
  __syncthreads();

  int cur = 0;
  for (int t = 0; t < nk; ++t) {
    if (t + 1 < nk) {
      const int k = (t + 1) * BK;
#pragma unroll
      for (int qq = 0; qq < 4; ++qq) {
        gll16(srcA[qq] + k, &As[cur ^ 1][awb + qq * 8][0]);
        gll16(srcB[qq] + k, &Bs[cur ^ 1][awb + qq * 8][0]);
      }
    }
    short8 ah[4], al[4], bh[4], bl[4];
#pragma unroll
    for (int i = 0; i < 4; ++i) {
      const int rA = wm + i*16 + l15;
      const int xr = (rA & 7) << 3;
      ah[i] = *(const short8*)&As[cur][rA][(s8)      ^ xr];
      al[i] = *(const short8*)&As[cur][rA][(s8 + 32) ^ xr];
    }
#pragma unroll
    for (int j = 0; j < 4; ++j) {
      const int rB = wn + j*16 + l15;
      const int xr = (rB & 7) << 3;
      bh[j] = *(const short8*)&Bs[cur][rB][(s8)      ^ xr];
      bl[j] = *(const short8*)&Bs[cur][rB][(s8 + 32) ^ xr];
    }
#pragma unroll
    for (int j = 0; j < 4; ++j)
#pragma unroll
      for (int i = 0; i < 4; ++i) {
        acc[i][j] = __builtin_amdgcn_mfma_f32_16x16x32_bf16(ah[i], bh[j], acc[i][j], 0, 0, 0);
        acc[i][j] = __builtin_amdgcn_mfma_f32_16x16x32_bf16(al[i], bh[j], acc[i][j], 0, 0, 0);
        acc[i][j] = __builtin_amdgcn_mfma_f32_16x16x32_bf16(ah[i], bl[j], acc[i][j], 0, 0, 0);
      }
    __syncthreads();   // drains next-tile gload_lds (vmcnt) + read/write order
    cur ^= 1;
  }

#pragma unroll
  for (int j = 0; j < 4; ++j) {
    int col = bn + wn + j*16 + l15;
    if (col >= N) continue;
    float bv = (OUT == 0 && bias) ? bias[col] : 0.f;
#pragma unroll
    for (int i = 0; i < 4; ++i) {
      int row0 = bm + wm + i*16 + rr0;
#pragma unroll
      for (int rr = 0; rr < 4; ++rr) {
        int row = row0 + rr;
        if (row >= M) continue;
        float v = acc[i][j][rr] + bv;
        if (OUT == 0) {
          if (ACT == 1) v = fmaxf(v, 0.f);
          C[(size_t)row * ldc + col] = v;
        } else {
          // fused: v = t_z ; h = mask*((1-z)*sum_h + z*tanh(c_h + t_h))
          size_t oc = (size_t)row * LDI + col;
          size_t op = (size_t)row * KP + col;
          float z     = sigmoidf_(CHp[oc] + v);
          float sum_h = bf16tof(smh[op]) + bf16tof(sml[op]);
          float pre   = tanhf(CHp[oc + 450] + thp[(size_t)row * H + col]);
          float hv    = (1.f - z) * sum_h + z * pre;
          if (row == 0) hv = 0.f;
          short hi, lo; bf16split(hv, hi, lo);
          oh[op] = hi; ol[op] = lo;
        }
      }
    }
  }
}

// ---------------- weight transpose + bf16 hi/lo split ----------------
// Bt[c][k] = W[k][c] for c < rmax (rows >= Kreal / cols >= H zero-filled)
__global__ __launch_bounds__(256)
void k_wT(const float* __restrict__ W, int Kreal,
          short* __restrict__ Bth, short* __restrict__ Btl, int Kpad, int rmax) {
  __shared__ float T[32][33];
  const int tx = threadIdx.x & 31;
  const int ty = threadIdx.x >> 5;
  const int k0 = blockIdx.x * 32;
  const int c0 = blockIdx.y * 32;
#pragma unroll
  for (int i = 0; i < 4; ++i) {
    int k = k0 + ty + i*8, c = c0 + tx;
    T[ty + i*8][tx] = (k < Kreal && c < H) ? W[(size_t)k * H + c] : 0.f;
  }
  __syncthreads();
#pragma unroll
  for (int i = 0; i < 4; ++i) {
    int c = c0 + ty + i*8, k = k0 + tx;
    if (k < Kpad && c < rmax) {
      short hi, lo;
      bf16split(T[tx][ty + i*8], hi, lo);
      Bth[(size_t)c * Kpad + k] = hi;
      Btl[(size_t)c * Kpad + k] = lo;
    }
  }
}

__global__ void k_biascat(const float* __restrict__ bz, const float* __restrict__ bh,
                          const float* __restrict__ bu, float* __restrict__ biasI) {
  int c = blockIdx.x * blockDim.x + threadIdx.x;
  if (c >= 1408) return;
  float v = 0.f;
  if (c < 450) v = bz[c];
  else if (c < 900) v = bh[c - 450];
  else if (c < 1350) v = bu[c - 900];
  biasI[c] = v;
}

// ---------------- elementwise / gather kernels ----------------

__global__ void k_build_idx(const int* __restrict__ fnode,
                            const int* __restrict__ fmess,
                            int* __restrict__ idxM) {
  int m = blockIdx.x * blockDim.x + threadIdx.x;
  if (m < NMESS) idxM[m] = fnode[fmess[m]];
}

__global__ void k_embsplit(const float* __restrict__ emb,
                           const int* __restrict__ idxM,
                           short* __restrict__ eh, short* __restrict__ el) {
  int m = blockIdx.x, j = threadIdx.x * 2;
  if (j >= H) return;
  float2 v = *(const float2*)&emb[(size_t)idxM[m] * H + j];
  short2 h2, l2;
  bf16split(v.x, h2.x, l2.x); bf16split(v.y, h2.y, l2.y);
  size_t o = (size_t)m * KP + j;
  *(short2*)&eh[o] = h2; *(short2*)&el[o] = l2;
}

// one pass over neighbors: sum_h planes + sum_gh planes
__global__ void k_gather2(const short* __restrict__ hh, const short* __restrict__ hl,
                          const float* __restrict__ g,
                          const float* __restrict__ CHp,   // r1b at +900, stride LDI
                          const int* __restrict__ mg,
                          short* __restrict__ shh, short* __restrict__ shl,
                          short* __restrict__ ghh, short* __restrict__ ghl) {
  int m = blockIdx.x, j = threadIdx.x * 2;
  if (j >= H) return;
  const int* e = mg + (size_t)m * KM;
  float2 rb = *(const float2*)&CHp[(size_t)m * LDI + 900 + j];
  float s0 = 0.f, s1 = 0.f, t0 = 0.f, t1 = 0.f;
#pragma unroll
  for (int k = 0; k < KM; ++k) {
    int ek = e[k];
    size_t oP = (size_t)ek * KP + j;
    float2 gv = *(const float2*)&g[(size_t)ek * H + j];
    short2 ph = *(const short2*)&hh[oP];
    short2 pl = *(const short2*)&hl[oP];
    float h0 = bf16tof(ph.x) + bf16tof(pl.x);
    float h1 = bf16tof(ph.y) + bf16tof(pl.y);
    s0 += h0;                          s1 += h1;
    t0 += sigmoidf_(rb.x + gv.x) * h0; t1 += sigmoidf_(rb.y + gv.y) * h1;
  }
  size_t o = (size_t)m * KP + j;
  short2 h2, l2;
  bf16split(s0, h2.x, l2.x); bf16split(s1, h2.y, l2.y);
  *(short2*)&shh[o] = h2; *(short2*)&shl[o] = l2;
  bf16split(t0, h2.x, l2.x); bf16split(t1, h2.y, l2.y);
  *(short2*)&ghh[o] = h2; *(short2*)&ghl[o] = l2;
}

// Acat planes [n][960] = [split(emb[fnode[n]]), split(sum_k h[ng[n,k]]), 0-pad]
__global__ void k_nodecat(const float* __restrict__ emb,
                          const int* __restrict__ fnode,
                          const short* __restrict__ hh, const short* __restrict__ hl,
                          const int* __restrict__ ng,
                          short* __restrict__ Ah, short* __restrict__ Al) {
  int n = blockIdx.x, t = threadIdx.x, j = t * 2;
  if (j < H) {
    float2 v = *(const float2*)&emb[(size_t)fnode[n] * H + j];
    short2 h2, l2;
    bf16split(v.x, h2.x, l2.x); bf16split(v.y, h2.y, l2.y);
    size_t o = (size_t)n * KP2 + j;
    *(short2*)&Ah[o] = h2; *(short2*)&Al[o] = l2;

    const int* e = ng + (size_t)n * KN;
    float s0 = 0.f, s1 = 0.f;
#pragma unroll
    for (int k = 0; k < KN; ++k) {
      size_t oP = (size_t)e[k] * KP + j;
      short2 ph = *(const short2*)&hh[oP];
      short2 pl = *(const short2*)&hl[oP];
      s0 += bf16tof(ph.x) + bf16tof(pl.x);
      s1 += bf16tof(ph.y) + bf16tof(pl.y);
    }
    bf16split(s0, h2.x, l2.x); bf16split(s1, h2.y, l2.y);
    o = (size_t)n * KP2 + H + j;
    *(short2*)&Ah[o] = h2; *(short2*)&Al[o] = l2;
  }
  if (t < 30) {   // zero cols [900,960)
    short2 z2; z2.x = 0; z2.y = 0;
    size_t o = (size_t)n * KP2 + H2 + t * 2;
    *(short2*)&Ah[o] = z2; *(short2*)&Al[o] = z2;
  }
}

// ---------------- launch ----------------

extern "C" void kernel_launch(void* const* d_in, const int* in_sizes, int n_in,
                              void* d_out, int out_size, void* d_ws, size_t ws_size,
                              hipStream_t stream) {
  (void)in_sizes; (void)n_in; (void)out_size; (void)ws_size;

  const int*   fnode      = (const int*)d_in[0];
  const int*   fmess      = (const int*)d_in[1];
  const int*   node_graph = (const int*)d_in[2];
  const int*   mess_graph = (const int*)d_in[3];
  const float* emb        = (const float*)d_in[4];
  const float* Wz         = (const float*)d_in[5];
  const float* bz         = (const float*)d_in[6];
  const float* Wr         = (const float*)d_in[7];
  const float* Ur         = (const float*)d_in[8];
  const float* bu         = (const float*)d_in[9];
  const float* Wh         = (const float*)d_in[10];
  const float* bh         = (const float*)d_in[11];
  const float* Wo         = (const float*)d_in[12];
  const float* bo         = (const float*)d_in[13];

  // ---- workspace (123.5 MB, proven budget) ----
  float* CH  = (float*)d_ws;                       // [M][1350]: c_z|c_h|r1b
  float* g   = CH + (size_t)NMESS * LDI;           // [M][450]: Ur out, then t_h
  short* P   = (short*)(g + (size_t)NMESS * H);
  short* hSh  = P;
  short* hSl  = P + 1 * PSZ;
  short* shSh = P + 2 * PSZ;     // sum_h hi (later Acat hi, stride 960)
  short* shSl = P + 3 * PSZ;
  short* ghSh = P + 4 * PSZ;     // sum_gh hi (also fmess_e hi)

  // ---- d_out messages region (17.6 of 18.4 MB) ----
  char*  scr   = (char*)d_out + (size_t)NNODE * H * 4;
  int*   idxM  = (int*)scr;                          // 40,964 B
  float* biasI = (float*)(scr + 40976);              // 1408 f32
  short* BtIh  = (short*)(scr + 46608);              // [1408][480]
  short* BtIl  = BtIh  + (size_t)1408 * KP;
  short* BtUrh = BtIl  + (size_t)1408 * KP;          // [512][480] each below
  short* BtUrl = BtUrh + (size_t)512 * KP;
  short* BtZh  = BtUrl + (size_t)512 * KP;           // Wz bottom
  short* BtZl  = BtZh  + (size_t)512 * KP;
  short* BtHh  = BtZl  + (size_t)512 * KP;           // Wh bottom
  short* BtHl  = BtHh  + (size_t)512 * KP;
  short* BtOh  = BtHl  + (size_t)512 * KP;           // Wo [512][960]
  short* BtOl  = BtOh  + (size_t)512 * KP2;
  short* ghSl  = BtOl  + (size_t)512 * KP2;          // sum_gh lo plane

  // zero planes (pads must be 0 / h0 = 0) + scratch region
  hipMemsetAsync(P, 0, 5 * PSZ * sizeof(short), stream);
  hipMemsetAsync(scr, 0, (size_t)NMESS * H * sizeof(float), stream);

  k_build_idx<<<(NMESS + 255) / 256, 256, 0, stream>>>(fnode, fmess, idxM);

  // weight prep: merged invariant [Wz_t | Wh_t | Wr] rows 0/450/900, then GRU/out mats
  dim3 gT(KP / 32, 16), gT2(KP2 / 32, 16);
  k_wT<<<gT,  256, 0, stream>>>(Wz,                  H, BtIh,            BtIl,            KP, 512);
  k_wT<<<gT,  256, 0, stream>>>(Wh,                  H, BtIh + 450 * KP, BtIl + 450 * KP, KP, 512);
  k_wT<<<gT,  256, 0, stream>>>(Wr,                  H, BtIh + 900 * KP, BtIl + 900 * KP, KP, 508);
  k_wT<<<gT,  256, 0, stream>>>(Ur,                  H, BtUrh, BtUrl, KP, 512);
  k_wT<<<gT,  256, 0, stream>>>(Wz + (size_t)H * H,  H, BtZh,  BtZl,  KP, 512);
  k_wT<<<gT,  256, 0, stream>>>(Wh + (size_t)H * H,  H, BtHh,  BtHl,  KP, 512);
  k_wT<<<gT2, 256, 0, stream>>>(Wo,                 H2, BtOh,  BtOl,  KP2, 512);
  k_biascat<<<6, 256, 0, stream>>>(bz, bh, bu, biasI);

  // fmess_e split into ghS pair
  k_embsplit<<<NMESS, 256, 0, stream>>>(emb, idxM, ghSh, ghSl);

  // merged invariant GEMM: CH = fmess_e @ [WzT|WhT|Wr] + [bz|bh|bu]
  dim3 gI(11, MPAD / BM);
  gemm3<0,0><<<gI, 256, 0, stream>>>(ghSh, ghSl, KP, BtIh, BtIl, biasI,
                                     CH, LDI, NMESS, LDI,
                                     nullptr, nullptr, nullptr, nullptr, nullptr, nullptr);

  dim3 gB(4, MPAD / BM);
  for (int d = 0; d < 8; ++d) {
    // g = h @ Ur
    gemm3<0,0><<<gB, 256, 0, stream>>>(hSh, hSl, KP, BtUrh, BtUrl, nullptr,
                                       g, H, NMESS, H,
                                       nullptr, nullptr, nullptr, nullptr, nullptr, nullptr);
    // sum_h & sum_gh planes in one pass
    k_gather2<<<NMESS, 256, 0, stream>>>(hSh, hSl, g, CH, mess_graph, shSh, shSl, ghSh, ghSl);
    // t_h = sum_gh @ WhB -> g (dead)
    gemm3<0,0><<<gB, 256, 0, stream>>>(ghSh, ghSl, KP, BtHh, BtHl, nullptr,
                                       g, H, NMESS, H,
                                       nullptr, nullptr, nullptr, nullptr, nullptr, nullptr);
    // t_z = sum_h @ WzB, fused combine -> h planes
    gemm3<0,2><<<gB, 256, 0, stream>>>(shSh, shSl, KP, BtZh, BtZl, nullptr,
                                       nullptr, 0, NMESS, H,
                                       CH, g, shSh, shSl, hSh, hSl);
  }

  // Acat planes (stride 960) then output GEMM with relu
  k_nodecat<<<NNODE, 256, 0, stream>>>(emb, fnode, hSh, hSl, node_graph, shSh, shSl);
  dim3 gF(4, NNODE / BM);
  gemm3<1,0><<<gF, 256, 0, stream>>>(shSh, shSl, KP2, BtOh, BtOl, bo,
                                     (float*)d_out, H, NNODE, H,
                                     nullptr, nullptr, nullptr, nullptr, nullptr, nullptr);

  // messages output = zeros (wipes idx + weights + ghSl) — AFTER final GEMM
  hipMemsetAsync((float*)d_out + (size_t)NNODE * H, 0, (size_t)NMESS * H * sizeof(float), stream);
}

// Round 8
// 1523.352 us; speedup vs baseline: 1.0662x; 1.0380x over previous
//
#include <hip/hip_runtime.h>
#include <cstdint>
#include <cstddef>

#define H 450
#define H2 900
#define KP 480
#define KP2 960
#define NMESS 10241
#define NNODE 5120
#define MPAD 10368                 // 162 * 64
#define PSZ ((size_t)MPAD * KP)    // plane size in shorts = 4,976,640
#define KM 5
#define KN 6
#define LDI 1350                   // CH row stride (c_z | c_h | r1b)

typedef __attribute__((ext_vector_type(8))) short short8;   // 8 bf16
typedef __attribute__((ext_vector_type(4))) float f32x4;

__device__ __forceinline__ short bf16rne(float f) {
  union { float f; unsigned u; } x; x.f = f;
  unsigned u = x.u;
  u += 0x7FFF + ((u >> 16) & 1);
  return (short)(u >> 16);
}
__device__ __forceinline__ float bf16tof(short s) {
  union { float f; unsigned u; } x;
  x.u = ((unsigned)(unsigned short)s) << 16;
  return x.f;
}
__device__ __forceinline__ void bf16split(float v, short& hi, short& lo) {
  hi = bf16rne(v);
  lo = bf16rne(v - bf16tof(hi));
}
__device__ __forceinline__ float sigmoidf_(float x) {
  return 1.f / (1.f + __expf(-x));
}

// direct global->LDS 16B DMA (LDS dest: wave-uniform base + lane*16)
__device__ __forceinline__ void gll16(const short* g, short* l) {
  __builtin_amdgcn_global_load_lds(
      (const __attribute__((address_space(1))) void*)g,
      (__attribute__((address_space(3))) void*)l, 16, 0, 0);
}

// ---------------- split-bf16 MFMA GEMM v6: 64x64 tiles ----------------
// 256 threads (4 waves, 32x32 wave tiles), BK=32, 32 KB LDS -> 5 blocks/CU.
// global_load_lds with pre-swizzled per-lane SOURCE slot = (lane&7)^(row&7);
// LDS fill linear; read-side XOR matches. Double-buffered, XCD swizzle.
#define BM 64
#define BN 64
#define BK 32

struct SmemT { short As[2][64][64]; short Bs[2][64][64]; };   // 32 KB

__device__ __forceinline__ void xcd_swz(int gx, int gy, int& bm, int& bn) {
  const int nwg = gx * gy;
  int lid = blockIdx.y * gx + blockIdx.x;
  const int q = nwg >> 3, r = nwg & 7;
  const int xcd = lid & 7, seq = lid >> 3;
  int sid = (xcd < r) ? (xcd * (q + 1) + seq)
                      : (r * (q + 1) + (xcd - r) * q + seq);
  bm = (sid / gx) * BM;
  bn = (sid % gx) * BN;
}

// OUT: 0 = f32 C (+bias, opt relu)   1 = split bf16 planes (ldc in shorts)
template<int ACT, int OUT>
__device__ __forceinline__ void gemm_core(
    SmemT& sm, const short* __restrict__ Ah, const short* __restrict__ Al,
    int Kpad, const short* __restrict__ Bth, const short* __restrict__ Btl,
    const float* __restrict__ bias,
    float* C, int ldc, short* Ch, short* Cl,
    int M, int N, int bm, int bn)
{
  const int tid  = threadIdx.x;
  const int lane = tid & 63;
  const int wid  = tid >> 6;          // 0..3
  const int wm   = (wid >> 1) * 32;
  const int wn   = (wid & 1) * 32;
  const int l15  = lane & 15;
  const int s8   = (lane >> 4) * 8;   // k sub-offset in halves
  const int rr0  = (lane >> 4) * 4;

  // staging: unified 128 rows (0-63 = A, 64-127 = B); wave wid -> rows 32w..32w+31
  const int lr = lane >> 3;
  const int sl = lane & 7;
  const int t0 = sl ^ lr;             // data slot fetched by this lane
  const short* src[4];
#pragma unroll
  for (int qq = 0; qq < 4; ++qq) {
    const int rrow = wid * 32 + qq * 8 + lr;
    const bool isA = rrow < 64;
    const int grow = isA ? (bm + rrow) : (bn + rrow - 64);
    const short* pl = isA ? (t0 < 4 ? Ah : Al) : (t0 < 4 ? Bth : Btl);
    src[qq] = pl + (size_t)grow * Kpad + (t0 & 3) * 8;
  }
  const int nk = Kpad / BK;

  f32x4 acc[2][2];
#pragma unroll
  for (int i = 0; i < 2; ++i)
#pragma unroll
    for (int j = 0; j < 2; ++j)
#pragma unroll
      for (int t = 0; t < 4; ++t) acc[i][j][t] = 0.f;

  auto STAGE = [&](int b, int koff) {
#pragma unroll
    for (int qq = 0; qq < 4; ++qq) {
      const int r0 = wid * 32 + qq * 8;
      short* d = (r0 < 64) ? &sm.As[b][r0][0] : &sm.Bs[b][r0 - 64][0];
      gll16(src[qq] + koff, d);
    }
  };

  STAGE(0, 0);
  __syncthreads();
  int cur = 0;
  for (int t = 0; t < nk; ++t) {
    if (t + 1 < nk) STAGE(cur ^ 1, (t + 1) * BK);
    short8 ah[2], al[2], bh[2], bl[2];
#pragma unroll
    for (int i = 0; i < 2; ++i) {
      const int rA = wm + i*16 + l15;
      const int xr = (rA & 7) << 3;
      ah[i] = *(const short8*)&sm.As[cur][rA][(s8)      ^ xr];
      al[i] = *(const short8*)&sm.As[cur][rA][(s8 + 32) ^ xr];
    }
#pragma unroll
    for (int j = 0; j < 2; ++j) {
      const int rB = wn + j*16 + l15;
      const int xr = (rB & 7) << 3;
      bh[j] = *(const short8*)&sm.Bs[cur][rB][(s8)      ^ xr];
      bl[j] = *(const short8*)&sm.Bs[cur][rB][(s8 + 32) ^ xr];
    }
#pragma unroll
    for (int j = 0; j < 2; ++j)
#pragma unroll
      for (int i = 0; i < 2; ++i) {
        acc[i][j] = __builtin_amdgcn_mfma_f32_16x16x32_bf16(ah[i], bh[j], acc[i][j], 0, 0, 0);
        acc[i][j] = __builtin_amdgcn_mfma_f32_16x16x32_bf16(al[i], bh[j], acc[i][j], 0, 0, 0);
        acc[i][j] = __builtin_amdgcn_mfma_f32_16x16x32_bf16(ah[i], bl[j], acc[i][j], 0, 0, 0);
      }
    __syncthreads();   // drains next-tile gload_lds + read/write order
    cur ^= 1;
  }

#pragma unroll
  for (int j = 0; j < 2; ++j) {
    int col = bn + wn + j*16 + l15;
    if (col >= N) continue;
    float bv = (OUT == 0 && bias) ? bias[col] : 0.f;
#pragma unroll
    for (int i = 0; i < 2; ++i) {
      int row0 = bm + wm + i*16 + rr0;
#pragma unroll
      for (int rr = 0; rr < 4; ++rr) {
        int row = row0 + rr;
        if (row >= M) continue;
        float v = acc[i][j][rr] + bv;
        if (OUT == 0) {
          if (ACT == 1) v = fmaxf(v, 0.f);
          C[(size_t)row * ldc + col] = v;
        } else {
          short hi, lo; bf16split(v, hi, lo);
          Ch[(size_t)row * ldc + col] = hi;
          Cl[(size_t)row * ldc + col] = lo;
        }
      }
    }
  }
}

template<int ACT>
__global__ __launch_bounds__(256, 4)
void gemm4(const short* __restrict__ Ah, const short* __restrict__ Al, int Kpad,
           const short* __restrict__ Bth, const short* __restrict__ Btl,
           const float* __restrict__ bias,
           float* C, int ldc, int M, int N)
{
  __shared__ SmemT sm;
  int bm, bn; xcd_swz(gridDim.x, gridDim.y, bm, bn);
  gemm_core<ACT, 0>(sm, Ah, Al, Kpad, Bth, Btl, bias, C, ldc, nullptr, nullptr, M, N, bm, bn);
}

// grouped: z=0: t_h = ghS@WhB -> g (f32); z=1: t_z = shS@WzB -> h planes (split)
__global__ __launch_bounds__(256, 4)
void gemm4_pair(const short* __restrict__ A0h, const short* __restrict__ A0l,
                const short* __restrict__ B0h, const short* __restrict__ B0l,
                float* C0,
                const short* __restrict__ A1h, const short* __restrict__ A1l,
                const short* __restrict__ B1h, const short* __restrict__ B1l,
                short* C1h, short* C1l)
{
  __shared__ SmemT sm;
  int bm, bn; xcd_swz(gridDim.x, gridDim.y, bm, bn);
  if (blockIdx.z == 0)
    gemm_core<0, 0>(sm, A0h, A0l, KP, B0h, B0l, nullptr, C0, H, nullptr, nullptr, NMESS, H, bm, bn);
  else
    gemm_core<0, 1>(sm, A1h, A1l, KP, B1h, B1l, nullptr, nullptr, KP, C1h, C1l, NMESS, H, bm, bn);
}

// ---------------- weight transpose + bf16 hi/lo split ----------------
__global__ __launch_bounds__(256)
void k_wT(const float* __restrict__ W, int Kreal,
          short* __restrict__ Bth, short* __restrict__ Btl, int Kpad, int rmax) {
  __shared__ float T[32][33];
  const int tx = threadIdx.x & 31;
  const int ty = threadIdx.x >> 5;
  const int k0 = blockIdx.x * 32;
  const int c0 = blockIdx.y * 32;
#pragma unroll
  for (int i = 0; i < 4; ++i) {
    int k = k0 + ty + i*8, c = c0 + tx;
    T[ty + i*8][tx] = (k < Kreal && c < H) ? W[(size_t)k * H + c] : 0.f;
  }
  __syncthreads();
#pragma unroll
  for (int i = 0; i < 4; ++i) {
    int c = c0 + ty + i*8, k = k0 + tx;
    if (k < Kpad && c < rmax) {
      short hi, lo;
      bf16split(T[tx][ty + i*8], hi, lo);
      Bth[(size_t)c * Kpad + k] = hi;
      Btl[(size_t)c * Kpad + k] = lo;
    }
  }
}

__global__ void k_biascat(const float* __restrict__ bz, const float* __restrict__ bh,
                          const float* __restrict__ bu, float* __restrict__ biasI) {
  int c = blockIdx.x * blockDim.x + threadIdx.x;
  if (c >= 1408) return;
  float v = 0.f;
  if (c < 450) v = bz[c];
  else if (c < 900) v = bh[c - 450];
  else if (c < 1350) v = bu[c - 900];
  biasI[c] = v;
}

// ---------------- elementwise / gather kernels ----------------

__global__ void k_build_idx(const int* __restrict__ fnode,
                            const int* __restrict__ fmess,
                            int* __restrict__ idxM) {
  int m = blockIdx.x * blockDim.x + threadIdx.x;
  if (m < NMESS) idxM[m] = fnode[fmess[m]];
}

__global__ void k_embsplit(const float* __restrict__ emb,
                           const int* __restrict__ idxM,
                           short* __restrict__ eh, short* __restrict__ el) {
  int m = blockIdx.x, j = threadIdx.x * 2;
  if (j >= H) return;
  float2 v = *(const float2*)&emb[(size_t)idxM[m] * H + j];
  short2 h2, l2;
  bf16split(v.x, h2.x, l2.x); bf16split(v.y, h2.y, l2.y);
  size_t o = (size_t)m * KP + j;
  *(short2*)&eh[o] = h2; *(short2*)&el[o] = l2;
}

// one pass over neighbors: sum_h planes + sum_gh planes
__global__ void k_gather2(const short* __restrict__ hh, const short* __restrict__ hl,
                          const float* __restrict__ g,
                          const float* __restrict__ CHp,   // r1b at +900, stride LDI
                          const int* __restrict__ mg,
                          short* __restrict__ shh, short* __restrict__ shl,
                          short* __restrict__ ghh, short* __restrict__ ghl) {
  int m = blockIdx.x, j = threadIdx.x * 2;
  if (j >= H) return;
  const int* e = mg + (size_t)m * KM;
  float2 rb = *(const float2*)&CHp[(size_t)m * LDI + 900 + j];
  float s0 = 0.f, s1 = 0.f, t0 = 0.f, t1 = 0.f;
#pragma unroll
  for (int k = 0; k < KM; ++k) {
    int ek = e[k];
    size_t oP = (size_t)ek * KP + j;
    float2 gv = *(const float2*)&g[(size_t)ek * H + j];
    short2 ph = *(const short2*)&hh[oP];
    short2 pl = *(const short2*)&hl[oP];
    float h0 = bf16tof(ph.x) + bf16tof(pl.x);
    float h1 = bf16tof(ph.y) + bf16tof(pl.y);
    s0 += h0;                          s1 += h1;
    t0 += sigmoidf_(rb.x + gv.x) * h0; t1 += sigmoidf_(rb.y + gv.y) * h1;
  }
  size_t o = (size_t)m * KP + j;
  short2 h2, l2;
  bf16split(s0, h2.x, l2.x); bf16split(s1, h2.y, l2.y);
  *(short2*)&shh[o] = h2; *(short2*)&shl[o] = l2;
  bf16split(t0, h2.x, l2.x); bf16split(t1, h2.y, l2.y);
  *(short2*)&ghh[o] = h2; *(short2*)&ghl[o] = l2;
}

// h = mask*((1-z)*sum_h + z*tanh(c_h+th)); tz read from h planes, overwritten in place
__global__ void k_combine(const float* __restrict__ CHp,
                          const float* __restrict__ th,
                          const short* __restrict__ shh, const short* __restrict__ shl,
                          short* hh, short* hl) {
  int m = blockIdx.x, j = threadIdx.x * 2;
  if (j >= H) return;
  size_t oc = (size_t)m * LDI + j;
  size_t op = (size_t)m * KP + j;
  size_t og = (size_t)m * H + j;
  float2 cz = *(const float2*)&CHp[oc];
  float2 ch = *(const float2*)&CHp[oc + 450];
  float2 tv = *(const float2*)&th[og];
  short2 tzh = *(const short2*)&hh[op];
  short2 tzl = *(const short2*)&hl[op];
  short2 smh = *(const short2*)&shh[op];
  short2 sml = *(const short2*)&shl[op];
  float tz0 = bf16tof(tzh.x) + bf16tof(tzl.x);
  float tz1 = bf16tof(tzh.y) + bf16tof(tzl.y);
  float sm0 = bf16tof(smh.x) + bf16tof(sml.x);
  float sm1 = bf16tof(smh.y) + bf16tof(sml.y);
  float z0 = sigmoidf_(cz.x + tz0);
  float z1 = sigmoidf_(cz.y + tz1);
  float p0 = tanhf(ch.x + tv.x);
  float p1 = tanhf(ch.y + tv.y);
  float v0 = (1.f - z0) * sm0 + z0 * p0;
  float v1 = (1.f - z1) * sm1 + z1 * p1;
  if (m == 0) { v0 = 0.f; v1 = 0.f; }
  short2 h2, l2;
  bf16split(v0, h2.x, l2.x); bf16split(v1, h2.y, l2.y);
  *(short2*)&hh[op] = h2; *(short2*)&hl[op] = l2;
}

// Acat planes [n][960] = [split(emb[fnode[n]]), split(sum_k h[ng[n,k]]), 0-pad]
__global__ void k_nodecat(const float* __restrict__ emb,
                          const int* __restrict__ fnode,
                          const short* __restrict__ hh, const short* __restrict__ hl,
                          const int* __restrict__ ng,
                          short* __restrict__ Ah, short* __restrict__ Al) {
  int n = blockIdx.x, t = threadIdx.x, j = t * 2;
  if (j < H) {
    float2 v = *(const float2*)&emb[(size_t)fnode[n] * H + j];
    short2 h2, l2;
    bf16split(v.x, h2.x, l2.x); bf16split(v.y, h2.y, l2.y);
    size_t o = (size_t)n * KP2 + j;
    *(short2*)&Ah[o] = h2; *(short2*)&Al[o] = l2;

    const int* e = ng + (size_t)n * KN;
    float s0 = 0.f, s1 = 0.f;
#pragma unroll
    for (int k = 0; k < KN; ++k) {
      size_t oP = (size_t)e[k] * KP + j;
      short2 ph = *(const short2*)&hh[oP];
      short2 pl = *(const short2*)&hl[oP];
      s0 += bf16tof(ph.x) + bf16tof(pl.x);
      s1 += bf16tof(ph.y) + bf16tof(pl.y);
    }
    bf16split(s0, h2.x, l2.x); bf16split(s1, h2.y, l2.y);
    o = (size_t)n * KP2 + H + j;
    *(short2*)&Ah[o] = h2; *(short2*)&Al[o] = l2;
  }
  if (t < 30) {   // zero cols [900,960)
    short2 z2; z2.x = 0; z2.y = 0;
    size_t o = (size_t)n * KP2 + H2 + t * 2;
    *(short2*)&Ah[o] = z2; *(short2*)&Al[o] = z2;
  }
}

// ---------------- launch ----------------

extern "C" void kernel_launch(void* const* d_in, const int* in_sizes, int n_in,
                              void* d_out, int out_size, void* d_ws, size_t ws_size,
                              hipStream_t stream) {
  (void)in_sizes; (void)n_in; (void)out_size; (void)ws_size;

  const int*   fnode      = (const int*)d_in[0];
  const int*   fmess      = (const int*)d_in[1];
  const int*   node_graph = (const int*)d_in[2];
  const int*   mess_graph = (const int*)d_in[3];
  const float* emb        = (const float*)d_in[4];
  const float* Wz         = (const float*)d_in[5];
  const float* bz         = (const float*)d_in[6];
  const float* Wr         = (const float*)d_in[7];
  const float* Ur         = (const float*)d_in[8];
  const float* bu         = (const float*)d_in[9];
  const float* Wh         = (const float*)d_in[10];
  const float* bh         = (const float*)d_in[11];
  const float* Wo         = (const float*)d_in[12];
  const float* bo         = (const float*)d_in[13];

  // ---- workspace (123.5 MB, proven budget) ----
  float* CH  = (float*)d_ws;                       // [M][1350]: c_z|c_h|r1b
  float* g   = CH + (size_t)NMESS * LDI;           // [M][450]: Ur out, then t_h
  short* P   = (short*)(g + (size_t)NMESS * H);
  short* hSh  = P;
  short* hSl  = P + 1 * PSZ;
  short* shSh = P + 2 * PSZ;     // sum_h hi (later Acat hi, stride 960)
  short* shSl = P + 3 * PSZ;
  short* ghSh = P + 4 * PSZ;     // sum_gh hi (also fmess_e hi)

  // ---- d_out messages region (17.6 of 18.4 MB) ----
  char*  scr   = (char*)d_out + (size_t)NNODE * H * 4;
  int*   idxM  = (int*)scr;                          // 40,964 B
  float* biasI = (float*)(scr + 40976);              // 1408 f32
  short* BtIh  = (short*)(scr + 46608);              // [1408][480]
  short* BtIl  = BtIh  + (size_t)1408 * KP;
  short* BtUrh = BtIl  + (size_t)1408 * KP;          // [512][480] each below
  short* BtUrl = BtUrh + (size_t)512 * KP;
  short* BtZh  = BtUrl + (size_t)512 * KP;           // Wz bottom
  short* BtZl  = BtZh  + (size_t)512 * KP;
  short* BtHh  = BtZl  + (size_t)512 * KP;           // Wh bottom
  short* BtHl  = BtHh  + (size_t)512 * KP;
  short* BtOh  = BtHl  + (size_t)512 * KP;           // Wo [512][960]
  short* BtOl  = BtOh  + (size_t)512 * KP2;
  short* ghSl  = BtOl  + (size_t)512 * KP2;          // sum_gh lo plane

  // zero planes (pads must be 0 / h0 = 0) + scratch region
  hipMemsetAsync(P, 0, 5 * PSZ * sizeof(short), stream);
  hipMemsetAsync(scr, 0, (size_t)NMESS * H * sizeof(float), stream);

  k_build_idx<<<(NMESS + 255) / 256, 256, 0, stream>>>(fnode, fmess, idxM);

  // weight prep: merged invariant [Wz_t | Wh_t | Wr] rows 0/450/900, then GRU/out mats
  dim3 gT(KP / 32, 16), gT2(KP2 / 32, 16);
  k_wT<<<gT,  256, 0, stream>>>(Wz,                  H, BtIh,            BtIl,            KP, 512);
  k_wT<<<gT,  256, 0, stream>>>(Wh,                  H, BtIh + 450 * KP, BtIl + 450 * KP, KP, 512);
  k_wT<<<gT,  256, 0, stream>>>(Wr,                  H, BtIh + 900 * KP, BtIl + 900 * KP, KP, 508);
  k_wT<<<gT,  256, 0, stream>>>(Ur,                  H, BtUrh, BtUrl, KP, 512);
  k_wT<<<gT,  256, 0, stream>>>(Wz + (size_t)H * H,  H, BtZh,  BtZl,  KP, 512);
  k_wT<<<gT,  256, 0, stream>>>(Wh + (size_t)H * H,  H, BtHh,  BtHl,  KP, 512);
  k_wT<<<gT2, 256, 0, stream>>>(Wo,                 H2, BtOh,  BtOl,  KP2, 512);
  k_biascat<<<6, 256, 0, stream>>>(bz, bh, bu, biasI);

  // fmess_e split into ghS pair
  k_embsplit<<<NMESS, 256, 0, stream>>>(emb, idxM, ghSh, ghSl);

  // merged invariant GEMM: CH = fmess_e @ [WzT|WhT|Wr] + [bz|bh|bu]
  dim3 gI(22, MPAD / BM);          // (22, 162)
  gemm4<0><<<gI, 256, 0, stream>>>(ghSh, ghSl, KP, BtIh, BtIl, biasI, CH, LDI, NMESS, LDI);

  dim3 gB(8, MPAD / BM);           // (8, 162)
  dim3 gP(8, MPAD / BM, 2);        // grouped t_h + t_z
  for (int d = 0; d < 8; ++d) {
    // g = h @ Ur
    gemm4<0><<<gB, 256, 0, stream>>>(hSh, hSl, KP, BtUrh, BtUrl, nullptr, g, H, NMESS, H);
    // sum_h & sum_gh planes in one pass
    k_gather2<<<NMESS, 256, 0, stream>>>(hSh, hSl, g, CH, mess_graph, shSh, shSl, ghSh, ghSl);
    // t_h = ghS@WhB -> g (dead)  ||  t_z = shS@WzB -> h planes (old h dead)
    gemm4_pair<<<gP, 256, 0, stream>>>(ghSh, ghSl, BtHh, BtHl, g,
                                       shSh, shSl, BtZh, BtZl, hSh, hSl);
    // combine in place (tz in h planes -> h)
    k_combine<<<NMESS, 256, 0, stream>>>(CH, g, shSh, shSl, hSh, hSl);
  }

  // Acat planes (stride 960) then output GEMM with relu
  k_nodecat<<<NNODE, 256, 0, stream>>>(emb, fnode, hSh, hSl, node_graph, shSh, shSl);
  dim3 gF(8, NNODE / BM);          // (8, 80)
  gemm4<1><<<gF, 256, 0, stream>>>(shSh, shSl, KP2, BtOh, BtOl, bo, (float*)d_out, H, NNODE, H);

  // messages output = zeros (wipes idx + weights + ghSl) — AFTER final GEMM
  hipMemsetAsync((float*)d_out + (size_t)NNODE * H, 0, (size_t)NMESS * H * sizeof(float), stream);
}